// Round 7
// baseline (263.318 us; speedup 1.0000x reference)
//
#include <hip/hip_runtime.h>
#include <cstddef>

// Problem constants (fixed by setup_inputs)
#define BB 4
#define QQ 4096
#define MM 8
#define NN 21760

typedef __bf16 bf16_8 __attribute__((ext_vector_type(8)));
typedef __bf16 bf16_4 __attribute__((ext_vector_type(4)));
typedef float  floatx4 __attribute__((ext_vector_type(4)));

// ---------------------------------------------------------------------------
// Weight prep: fp32 W[K][N] -> bf16 Wt[N][K].
// Wt layout (bf16): Wval[256x256] | Wq[384x256] (attn 0..127 | off 128..383) |
//                   Wout[256x256].  Also biasq[384] = [b_attn | b_off] fp32.
// ---------------------------------------------------------------------------
__global__ __launch_bounds__(256) void prep_weights(
    const float* __restrict__ Wv, const float* __restrict__ Wa,
    const float* __restrict__ Wo, const float* __restrict__ Wu,
    const float* __restrict__ ba, const float* __restrict__ bo,
    __bf16* __restrict__ Wt, float* __restrict__ biasq)
{
    const int gid = blockIdx.x * 256 + threadIdx.x;
    if (gid < 65536) {
        const int n = gid >> 8, k = gid & 255;
        Wt[gid] = (__bf16)Wv[k * 256 + n];
    } else if (gid < 163840) {
        const int o = gid - 65536;
        const int n = o >> 8, k = o & 255;
        Wt[gid] = (__bf16)(n < 128 ? Wa[k * 128 + n] : Wo[k * 256 + (n - 128)]);
    } else if (gid < 229376) {
        const int o = gid - 163840;
        const int n = o >> 8, k = o & 255;
        Wt[gid] = (__bf16)Wu[k * 256 + n];
    } else if (gid < 229760) {
        const int j = gid - 229376;
        biasq[j] = (j < 128) ? ba[j] : bo[j - 128];
    }
}

// ---------------------------------------------------------------------------
// bf16 MFMA GEMM, operand-swapped + B-direct + A-dbuf.
//   D[feature][token] = W(A-op, from global) x Act(B-op, from LDS)
// Tile: 64 tokens x NCOLS features, 256 threads (4 waves split features).
// BK=64, 4 K-iters, ONE barrier per iter (A-only LDS, double-buffered;
// weights go global->VGPR directly, L2-hot, no LDS).
// Epilogue: lane holds 4 consecutive features per frag -> float4 / bf16_4
// vector stores; bias as one float4.
// AT = float (cvt while staging) or __bf16.
// MODE 0: fp32 store at Cout[(z*tokens+token)*ldc + n]  (Cout/bias may be
//         column-offset by the caller)
// MODE 1: bf16 v_p store at [((z*8 + n/32)*NN + token)*32 + n%32]
// ---------------------------------------------------------------------------
template<typename AT, int NCOLS, int MODE>
__global__ __launch_bounds__(256) void gemm_bd(
    const AT* __restrict__ A,
    const __bf16* __restrict__ Wn,     // [NCOLS][256] bf16 (n-major)
    const float* __restrict__ bias,
    void* __restrict__ Cout,
    int tokens, int ldc)
{
    constexpr int NJ = NCOLS / 64;     // feature frags per wave
    const int z    = blockIdx.z;
    const int row0 = blockIdx.y * 64;
    const AT* Ab = A + (size_t)z * tokens * 256;

    __shared__ __bf16 As[2][64][68];   // activation tiles (dbuf), pad 68: 0 conflicts measured

    const int tid  = threadIdx.x;
    const int lane = tid & 63;
    const int wave = tid >> 6;
    const int quad = lane >> 4;
    const int l16  = lane & 15;
    const int wave_f = wave * (NCOLS / 4);

    floatx4 acc[NJ][4] = {};           // [feature frag][token frag]

    // ---- prologue: stage activation tile k0=0 into buffer 0 ----
    if (sizeof(AT) == 4) {
        const float* Af = (const float*)Ab;
        #pragma unroll
        for (int c = 0; c < 4; ++c) {
            const int cid = c * 256 + tid;
            const int r   = cid >> 4;
            const int kc  = (cid & 15) * 4;
            const float4 av = *(const float4*)(Af + (size_t)(row0 + r) * 256 + kc);
            bf16_4 w;
            w[0] = (__bf16)av.x; w[1] = (__bf16)av.y; w[2] = (__bf16)av.z; w[3] = (__bf16)av.w;
            *(bf16_4*)&As[0][r][kc] = w;
        }
    } else {
        const __bf16* Ah = (const __bf16*)Ab;
        #pragma unroll
        for (int c = 0; c < 2; ++c) {
            const int cid = c * 256 + tid;
            const int r   = cid >> 3;
            const int kc  = (cid & 7) * 8;
            *(bf16_8*)&As[0][r][kc] = *(const bf16_8*)(Ah + (size_t)(row0 + r) * 256 + kc);
        }
    }
    __syncthreads();

    for (int i = 0; i < 4; ++i) {
        const int k0  = i * 64;
        const int cur = i & 1;

        // prefetch next activation tile into registers (longest latency first)
        float4 a4[4]; bf16_8 a8[2];
        if (i < 3) {
            if (sizeof(AT) == 4) {
                const float* Af = (const float*)Ab;
                #pragma unroll
                for (int c = 0; c < 4; ++c) {
                    const int cid = c * 256 + tid;
                    const int r   = cid >> 4;
                    const int kc  = (cid & 15) * 4;
                    a4[c] = *(const float4*)(Af + (size_t)(row0 + r) * 256 + k0 + 64 + kc);
                }
            } else {
                const __bf16* Ah = (const __bf16*)Ab;
                #pragma unroll
                for (int c = 0; c < 2; ++c) {
                    const int cid = c * 256 + tid;
                    const int r   = cid >> 3;
                    const int kc  = (cid & 7) * 8;
                    a8[c] = *(const bf16_8*)(Ah + (size_t)(row0 + r) * 256 + k0 + 64 + kc);
                }
            }
        }

        // weight fragments straight from global (L2-hot, no LDS)
        bf16_8 wf[2][NJ];
        #pragma unroll
        for (int h = 0; h < 2; ++h)
            #pragma unroll
            for (int j = 0; j < NJ; ++j)
                wf[h][j] = *(const bf16_8*)(Wn + (size_t)(wave_f + j * 16 + l16) * 256
                                             + k0 + h * 32 + quad * 8);

        // activation fragments from LDS + MFMA
        #pragma unroll
        for (int h = 0; h < 2; ++h) {
            bf16_8 af[4];
            #pragma unroll
            for (int it = 0; it < 4; ++it)
                af[it] = *(const bf16_8*)&As[cur][it * 16 + l16][h * 32 + quad * 8];
            #pragma unroll
            for (int j = 0; j < NJ; ++j)
                #pragma unroll
                for (int it = 0; it < 4; ++it)
                    acc[j][it] = __builtin_amdgcn_mfma_f32_16x16x32_bf16(wf[h][j], af[it], acc[j][it], 0, 0, 0);
        }

        if (i < 3) {
            // stage next tile into the other buffer; one barrier per iter
            if (sizeof(AT) == 4) {
                #pragma unroll
                for (int c = 0; c < 4; ++c) {
                    const int cid = c * 256 + tid;
                    const int r   = cid >> 4;
                    const int kc  = (cid & 15) * 4;
                    bf16_4 w;
                    w[0] = (__bf16)a4[c].x; w[1] = (__bf16)a4[c].y;
                    w[2] = (__bf16)a4[c].z; w[3] = (__bf16)a4[c].w;
                    *(bf16_4*)&As[cur ^ 1][r][kc] = w;
                }
            } else {
                #pragma unroll
                for (int c = 0; c < 2; ++c) {
                    const int cid = c * 256 + tid;
                    const int r   = cid >> 3;
                    const int kc  = (cid & 7) * 8;
                    *(bf16_8*)&As[cur ^ 1][r][kc] = a8[c];
                }
            }
            __syncthreads();
        }
    }

    // epilogue: lane covers features n0..n0+3 (quad*4 aligned), token = l16-based
    #pragma unroll
    for (int j = 0; j < NJ; ++j) {
        const int n0 = wave_f + j * 16 + quad * 4;
        const float4 b4 = *(const float4*)(bias + n0);
        #pragma unroll
        for (int it = 0; it < 4; ++it) {
            const int token = row0 + it * 16 + l16;
            const float v0 = acc[j][it][0] + b4.x;
            const float v1 = acc[j][it][1] + b4.y;
            const float v2 = acc[j][it][2] + b4.z;
            const float v3 = acc[j][it][3] + b4.w;
            if (MODE == 0) {
                float4 o; o.x = v0; o.y = v1; o.z = v2; o.w = v3;
                *(float4*)((float*)Cout + ((size_t)z * tokens + token) * ldc + n0) = o;
            } else {
                const int mh = n0 >> 5, dd = n0 & 31;
                bf16_4 ob;
                ob[0] = (__bf16)v0; ob[1] = (__bf16)v1; ob[2] = (__bf16)v2; ob[3] = (__bf16)v3;
                *(bf16_4*)((__bf16*)Cout + (((size_t)z * 8 + mh) * NN + token) * 32 + dd) = ob;
            }
        }
    }
}

// ---------------------------------------------------------------------------
// Fused softmax + bilinear sampling (v4): 4-lanes-per-row gather +
// halving-tree shuffle reduction.  Block = 512 threads = 8 waves (wave = head).
// ---------------------------------------------------------------------------
__device__ __forceinline__ float bflo(unsigned u) { return __uint_as_float(u << 16); }
__device__ __forceinline__ float bfhi(unsigned u) { return __uint_as_float(u & 0xffff0000u); }

__global__ __launch_bounds__(512) void sampler(
    const __bf16* __restrict__ vp,    // [B,8,N,32] bf16
    const float* __restrict__ gqp,    // [B*Q,384]: 0..127 attn logits, 128..383 offsets
    const float* __restrict__ pref,   // [B*Q,4,2]
    __bf16* __restrict__ mid)         // [B*Q,256] bf16
{
    const int t    = threadIdx.x;
    const int m    = t >> 6;
    const int lane = t & 63;
    const int s    = lane >> 2;     // sample 0..15
    const int c    = lane & 3;      // 16B chunk 0..3
    const int l    = s >> 2;        // level
    const int bq   = blockIdx.x;
    const int b    = bq >> 12;      // Q = 4096

    const int   Hi = 128 >> l;      // 128,64,32,16 (square levels)
    const float Hf = (float)Hi;
    const int   base = (l == 0) ? 0 : (l == 1) ? 16384 : (l == 2) ? 20480 : 21504;

    // softmax over the 16 samples of this head (lane bits 2..5); logits O(1)
    const float logit = gqp[(size_t)bq * 384 + m * 16 + s];
    const float e = __expf(logit);
    float sum = e;
    #pragma unroll
    for (int k = 4; k < 64; k <<= 1) sum += __shfl_xor(sum, k, 64);
    const float a = e * __builtin_amdgcn_rcpf(sum);

    const float2 off = *(const float2*)(gqp + (size_t)bq * 384 + 128 + (m * 16 + s) * 2);
    const float2 pr  = *(const float2*)(pref + (size_t)bq * 8 + l * 2);

    const float x = fmaf(pr.x, Hf, off.x - 0.5f);
    const float y = fmaf(pr.y, Hf, off.y - 0.5f);
    const float x0f = floorf(x), y0f = floorf(y);
    const float lx = x - x0f, ly = y - y0f;
    const int x0 = (int)x0f, y0 = (int)y0f;
    const int cx0 = min(max(x0, 0), Hi - 1), cx1 = min(max(x0 + 1, 0), Hi - 1);
    const int cy0 = min(max(y0, 0), Hi - 1), cy1 = min(max(y0 + 1, 0), Hi - 1);
    const bool vx0 = (x0 >= 0) && (x0 < Hi), vx1 = (x0 + 1 >= 0) && (x0 + 1 < Hi);
    const bool vy0 = (y0 >= 0) && (y0 < Hi), vy1 = (y0 + 1 >= 0) && (y0 + 1 < Hi);
    const float w00 = a * (1.f - lx) * (1.f - ly) * ((vx0 && vy0) ? 1.f : 0.f);
    const float w10 = a * lx * (1.f - ly) * ((vx1 && vy0) ? 1.f : 0.f);
    const float w01 = a * (1.f - lx) * ly * ((vx0 && vy1) ? 1.f : 0.f);
    const float w11 = a * lx * ly * ((vx1 && vy1) ? 1.f : 0.f);

    const __bf16* vbase = vp + ((size_t)b * 8 + m) * NN * 32;
    const uint4 u00 = *((const uint4*)(vbase + (size_t)(base + cy0 * Hi + cx0) * 32) + c);
    const uint4 u10 = *((const uint4*)(vbase + (size_t)(base + cy0 * Hi + cx1) * 32) + c);
    const uint4 u01 = *((const uint4*)(vbase + (size_t)(base + cy1 * Hi + cx0) * 32) + c);
    const uint4 u11 = *((const uint4*)(vbase + (size_t)(base + cy1 * Hi + cx1) * 32) + c);

    float f[8];
    f[0] = w00*bflo(u00.x) + w10*bflo(u10.x) + w01*bflo(u01.x) + w11*bflo(u11.x);
    f[1] = w00*bfhi(u00.x) + w10*bfhi(u10.x) + w01*bfhi(u01.x) + w11*bfhi(u11.x);
    f[2] = w00*bflo(u00.y) + w10*bflo(u10.y) + w01*bflo(u01.y) + w11*bflo(u11.y);
    f[3] = w00*bfhi(u00.y) + w10*bfhi(u10.y) + w01*bfhi(u01.y) + w11*bfhi(u11.y);
    f[4] = w00*bflo(u00.z) + w10*bflo(u10.z) + w01*bflo(u01.z) + w11*bflo(u11.z);
    f[5] = w00*bfhi(u00.z) + w10*bfhi(u10.z) + w01*bfhi(u01.z) + w11*bfhi(u11.z);
    f[6] = w00*bflo(u00.w) + w10*bflo(u10.w) + w01*bflo(u01.w) + w11*bflo(u11.w);
    f[7] = w00*bfhi(u00.w) + w10*bfhi(u10.w) + w01*bfhi(u01.w) + w11*bfhi(u11.w);

    // Halving-tree reduction over the 16 samples (lane bits 2..5)
    const int b2 = (lane >> 2) & 1, b3 = (lane >> 3) & 1, b4i = (lane >> 4) & 1;
    #pragma unroll
    for (int j = 0; j < 4; ++j) {
        const float sel  = b2 ? f[j] : f[j + 4];
        const float recv = __shfl_xor(sel, 4, 64);
        f[j] = (b2 ? f[j + 4] : f[j]) + recv;
    }
    #pragma unroll
    for (int j = 0; j < 2; ++j) {
        const float sel  = b3 ? f[j] : f[j + 2];
        const float recv = __shfl_xor(sel, 8, 64);
        f[j] = (b3 ? f[j + 2] : f[j]) + recv;
    }
    {
        const float sel  = b4i ? f[0] : f[1];
        const float recv = __shfl_xor(sel, 16, 64);
        f[0] = (b4i ? f[1] : f[0]) + recv;
    }
    f[0] += __shfl_xor(f[0], 32, 64);

    if (!(lane & 32)) {
        const int chan = (c << 3) | (b2 << 2) | (b3 << 1) | b4i;
        mid[(size_t)bq * 256 + m * 32 + chan] = (__bf16)f[0];
    }
}

extern "C" void kernel_launch(void* const* d_in, const int* in_sizes, int n_in,
                              void* d_out, int out_size, void* d_ws, size_t ws_size,
                              hipStream_t stream) {
    const float* q      = (const float*)d_in[0];
    const float* p      = (const float*)d_in[1];
    const float* v      = (const float*)d_in[2];
    const float* W_off  = (const float*)d_in[5];
    const float* b_off  = (const float*)d_in[6];
    const float* W_attn = (const float*)d_in[7];
    const float* b_attn = (const float*)d_in[8];
    const float* W_val  = (const float*)d_in[9];
    const float* b_val  = (const float*)d_in[10];
    const float* W_out  = (const float*)d_in[11];
    const float* b_out  = (const float*)d_in[12];
    float* out = (float*)d_out;

    // Workspace layout:
    //   gqp   : float [16384*384]
    //   biasq : float [384]
    //   mid   : bf16  [16384*256]
    //   vpb   : bf16  [4*8*21760*32]
    //   Wt    : bf16  [229376]
    float*  gqp   = (float*)d_ws;
    float*  biasq = gqp + (size_t)16384 * 384;
    __bf16* mid   = (__bf16*)(biasq + 384);
    __bf16* vpb   = mid + (size_t)16384 * 256;
    __bf16* Wt    = vpb + (size_t)BB * 8 * NN * 32;
    __bf16* Wt_val  = Wt;
    __bf16* Wt_attn = Wt + 65536;             // rows 0..127 of Wq
    __bf16* Wt_off  = Wt + 65536 + 32768;     // rows 128..383 of Wq
    __bf16* Wt_out  = Wt + 163840;

    // 0) weights -> bf16 transposed (+ fused q-proj bias)
    prep_weights<<<898, 256, 0, stream>>>(W_val, W_attn, W_off, W_out, b_attn, b_off, Wt, biasq);

    // 1) v_p = v @ W_val + b_val -> bf16 [B,8,N,32]
    {
        dim3 grid(1, NN / 64, BB);                  // (1, 340, 4)
        gemm_bd<float, 256, 1><<<grid, 256, 0, stream>>>(v, Wt_val, b_val, vpb, NN, 0);
    }
    // 2a) attn logits = q @ W_attn + b_attn -> gqp cols 0..127 (ldc 384)
    {
        dim3 grid(1, (BB * QQ) / 64, 1);            // (1, 256)
        gemm_bd<float, 128, 0><<<grid, 256, 0, stream>>>(q, Wt_attn, biasq, gqp, BB * QQ, 384);
    }
    // 2b) offsets = q @ W_off + b_off -> gqp cols 128..383 (ldc 384)
    {
        dim3 grid(1, (BB * QQ) / 64, 1);            // (1, 256)
        gemm_bd<float, 256, 0><<<grid, 256, 0, stream>>>(q, Wt_off, biasq + 128, gqp + 128, BB * QQ, 384);
    }
    // 3) softmax + bilinear sampling -> mid bf16 [B*Q,256]
    sampler<<<BB * QQ, 512, 0, stream>>>(vpb, gqp, p, mid);
    // 4) out = mid @ W_out + b_out -> [B,Q,256]
    {
        dim3 grid(1, (BB * QQ) / 64, 1);            // (1, 256)
        gemm_bd<__bf16, 256, 0><<<grid, 256, 0, stream>>>(mid, Wt_out, b_out, out, BB * QQ, 256);
    }
}

// Round 8
// 252.128 us; speedup vs baseline: 1.0444x; 1.0444x over previous
//
#include <hip/hip_runtime.h>
#include <cstddef>

// Problem constants (fixed by setup_inputs)
#define BB 4
#define QQ 4096
#define MM 8
#define NN 21760

typedef __bf16 bf16_8 __attribute__((ext_vector_type(8)));
typedef __bf16 bf16_4 __attribute__((ext_vector_type(4)));
typedef float  floatx4 __attribute__((ext_vector_type(4)));

// ---------------------------------------------------------------------------
// Weight prep: fp32 W[K][N] -> bf16 Wt[N][K].
// Wt layout (bf16): Wval[256x256] | Wq[384x256] (attn 0..127 | off 128..383) |
//                   Wout[256x256].  Also biasq[384] = [b_attn | b_off] fp32.
// ---------------------------------------------------------------------------
__global__ __launch_bounds__(256) void prep_weights(
    const float* __restrict__ Wv, const float* __restrict__ Wa,
    const float* __restrict__ Wo, const float* __restrict__ Wu,
    const float* __restrict__ ba, const float* __restrict__ bo,
    __bf16* __restrict__ Wt, float* __restrict__ biasq)
{
    const int gid = blockIdx.x * 256 + threadIdx.x;
    if (gid < 65536) {
        const int n = gid >> 8, k = gid & 255;
        Wt[gid] = (__bf16)Wv[k * 256 + n];
    } else if (gid < 163840) {
        const int o = gid - 65536;
        const int n = o >> 8, k = o & 255;
        Wt[gid] = (__bf16)(n < 128 ? Wa[k * 128 + n] : Wo[k * 256 + (n - 128)]);
    } else if (gid < 229376) {
        const int o = gid - 163840;
        const int n = o >> 8, k = o & 255;
        Wt[gid] = (__bf16)Wu[k * 256 + n];
    } else if (gid < 229760) {
        const int j = gid - 229376;
        biasq[j] = (j < 128) ? ba[j] : bo[j - 128];
    }
}

// ---------------------------------------------------------------------------
// Weight-stationary bf16 MFMA GEMM.
// 512 threads = 8 waves; each wave owns F = NCOLS/8 output features.
// The wave's weight fragments (F x 256 k) are loaded from global ONCE per
// block into VGPRs (wf[8][NJ]); the block then loops over TILES token-tiles
// of 64, staging the activation tile in XOR-swizzled LDS (dbuf, exactly
// 64 KB, one barrier per tile, staging split in halves to cap live regs).
// This removes the per-64-token-tile re-read of the weight panel that
// saturated the vmem pipe in previous rounds (174 MB -> 43.5 MB on v_p).
// AT = float (cvt while staging) or __bf16.
// MODE 0: fp32 store at Cout[(z*tokens+token)*ldc + n]
// MODE 1: bf16 v_p store at [((z*8 + n/32)*NN + token)*32 + n%32]
// ---------------------------------------------------------------------------
template<typename AT, int NCOLS, int MODE, int TILES>
__global__ __launch_bounds__(512) void gemm_ws(
    const AT* __restrict__ A,
    const __bf16* __restrict__ Wn,     // [NCOLS][256] bf16 (n-major)
    const float* __restrict__ bias,
    void* __restrict__ Cout,
    int tokens, int ldc)
{
    constexpr int F  = NCOLS / 8;      // features per wave (16 or 32)
    constexpr int NJ = F / 16;         // feature frags per wave (1 or 2)

    const int z = blockIdx.z;
    const AT* Ab = A + (size_t)z * tokens * 256;

    // XOR-swizzled activation tiles: element (r, k) lives at column
    // ((k>>3) ^ (r&7))<<3 | (k&7).  Exactly 64 KB (2 x 64 x 256 bf16).
    __shared__ __bf16 As[2][64][256];

    const int tid  = threadIdx.x;
    const int lane = tid & 63;
    const int wave = tid >> 6;
    const int quad = lane >> 4;
    const int l16  = lane & 15;
    const int wave_f = wave * F;

    // ---- weights -> VGPRs, once ----
    bf16_8 wf[8][NJ];
    #pragma unroll
    for (int kk = 0; kk < 8; ++kk)
        #pragma unroll
        for (int j = 0; j < NJ; ++j)
            wf[kk][j] = *(const bf16_8*)(Wn + (size_t)(wave_f + j * 16 + l16) * 256
                                          + kk * 32 + quad * 8);

    const int tile0 = blockIdx.y * TILES;

    // ---- staging helpers (inlined by hand below) ----
    // fp32: 4 float4 per thread per half; bf16: 2 bf16_8 per half.

    // prologue: stage tile 0 (both halves) into buffer 0
    {
        const int token0 = tile0 * 64;
        if (sizeof(AT) == 4) {
            const float* Af = (const float*)Ab;
            #pragma unroll
            for (int h = 0; h < 2; ++h) {
                #pragma unroll
                for (int c = 0; c < 4; ++c) {
                    const int cid = c * 512 + tid;
                    const int r   = cid >> 5;
                    const int kc  = (cid & 31) * 4;
                    const int k   = h * 128 + kc;
                    const float4 av = *(const float4*)(Af + (size_t)(token0 + r) * 256 + k);
                    bf16_4 w;
                    w[0] = (__bf16)av.x; w[1] = (__bf16)av.y;
                    w[2] = (__bf16)av.z; w[3] = (__bf16)av.w;
                    const int col = ((((k >> 3) ^ (r & 7)) << 3) | (k & 7));
                    *(bf16_4*)&As[0][r][col] = w;
                }
            }
        } else {
            const __bf16* Ah = (const __bf16*)Ab;
            #pragma unroll
            for (int h = 0; h < 2; ++h) {
                #pragma unroll
                for (int c = 0; c < 2; ++c) {
                    const int cid = c * 512 + tid;
                    const int r   = cid >> 4;
                    const int kc  = (cid & 15) * 8;
                    const int k   = h * 128 + kc;
                    const bf16_8 av = *(const bf16_8*)(Ah + (size_t)(token0 + r) * 256 + k);
                    const int col = (((k >> 3) ^ (r & 7)) << 3);
                    *(bf16_8*)&As[0][r][col] = av;
                }
            }
        }
        __syncthreads();
    }

    #pragma unroll
    for (int t = 0; t < TILES; ++t) {
        const int cur    = t & 1;
        const int token0 = (tile0 + t) * 64;
        const bool more  = (t + 1 < TILES);
        const int ntok0  = token0 + 64;

        floatx4 acc[NJ][4] = {};

        // prefetch next tile, half 0
        float4 a4[4]; bf16_8 a8[2];
        if (more) {
            if (sizeof(AT) == 4) {
                const float* Af = (const float*)Ab;
                #pragma unroll
                for (int c = 0; c < 4; ++c) {
                    const int cid = c * 512 + tid;
                    const int r   = cid >> 5;
                    const int kc  = (cid & 31) * 4;
                    a4[c] = *(const float4*)(Af + (size_t)(ntok0 + r) * 256 + kc);
                }
            } else {
                const __bf16* Ah = (const __bf16*)Ab;
                #pragma unroll
                for (int c = 0; c < 2; ++c) {
                    const int cid = c * 512 + tid;
                    const int r   = cid >> 4;
                    const int kc  = (cid & 15) * 8;
                    a8[c] = *(const bf16_8*)(Ah + (size_t)(ntok0 + r) * 256 + kc);
                }
            }
        }

        // MFMA k = 0..127
        #pragma unroll
        for (int kk = 0; kk < 4; ++kk) {
            bf16_8 af[4];
            #pragma unroll
            for (int it = 0; it < 4; ++it)
                af[it] = *(const bf16_8*)&As[cur][it * 16 + l16]
                                           [(((kk * 4 + quad) ^ (l16 & 7)) << 3)];
            #pragma unroll
            for (int j = 0; j < NJ; ++j)
                #pragma unroll
                for (int it = 0; it < 4; ++it)
                    acc[j][it] = __builtin_amdgcn_mfma_f32_16x16x32_bf16(wf[kk][j], af[it], acc[j][it], 0, 0, 0);
        }

        // stage half 0 of next tile; prefetch half 1
        if (more) {
            if (sizeof(AT) == 4) {
                const float* Af = (const float*)Ab;
                #pragma unroll
                for (int c = 0; c < 4; ++c) {
                    const int cid = c * 512 + tid;
                    const int r   = cid >> 5;
                    const int kc  = (cid & 31) * 4;
                    bf16_4 w;
                    w[0] = (__bf16)a4[c].x; w[1] = (__bf16)a4[c].y;
                    w[2] = (__bf16)a4[c].z; w[3] = (__bf16)a4[c].w;
                    const int col = ((((kc >> 3) ^ (r & 7)) << 3) | (kc & 7));
                    *(bf16_4*)&As[cur ^ 1][r][col] = w;
                }
                #pragma unroll
                for (int c = 0; c < 4; ++c) {
                    const int cid = c * 512 + tid;
                    const int r   = cid >> 5;
                    const int kc  = (cid & 31) * 4;
                    a4[c] = *(const float4*)(Af + (size_t)(ntok0 + r) * 256 + 128 + kc);
                }
            } else {
                const __bf16* Ah = (const __bf16*)Ab;
                #pragma unroll
                for (int c = 0; c < 2; ++c) {
                    const int cid = c * 512 + tid;
                    const int r   = cid >> 4;
                    const int kc  = (cid & 15) * 8;
                    const int col = (((kc >> 3) ^ (r & 7)) << 3);
                    *(bf16_8*)&As[cur ^ 1][r][col] = a8[c];
                }
                #pragma unroll
                for (int c = 0; c < 2; ++c) {
                    const int cid = c * 512 + tid;
                    const int r   = cid >> 4;
                    const int kc  = (cid & 15) * 8;
                    a8[c] = *(const bf16_8*)(Ah + (size_t)(ntok0 + r) * 256 + 128 + kc);
                }
            }
        }

        // MFMA k = 128..255
        #pragma unroll
        for (int kk = 4; kk < 8; ++kk) {
            bf16_8 af[4];
            #pragma unroll
            for (int it = 0; it < 4; ++it)
                af[it] = *(const bf16_8*)&As[cur][it * 16 + l16]
                                           [(((kk * 4 + quad) ^ (l16 & 7)) << 3)];
            #pragma unroll
            for (int j = 0; j < NJ; ++j)
                #pragma unroll
                for (int it = 0; it < 4; ++it)
                    acc[j][it] = __builtin_amdgcn_mfma_f32_16x16x32_bf16(wf[kk][j], af[it], acc[j][it], 0, 0, 0);
        }

        // stage half 1 of next tile
        if (more) {
            if (sizeof(AT) == 4) {
                #pragma unroll
                for (int c = 0; c < 4; ++c) {
                    const int cid = c * 512 + tid;
                    const int r   = cid >> 5;
                    const int kc  = (cid & 31) * 4;
                    const int k   = 128 + kc;
                    bf16_4 w;
                    w[0] = (__bf16)a4[c].x; w[1] = (__bf16)a4[c].y;
                    w[2] = (__bf16)a4[c].z; w[3] = (__bf16)a4[c].w;
                    const int col = ((((k >> 3) ^ (r & 7)) << 3) | (k & 7));
                    *(bf16_4*)&As[cur ^ 1][r][col] = w;
                }
            } else {
                #pragma unroll
                for (int c = 0; c < 2; ++c) {
                    const int cid = c * 512 + tid;
                    const int r   = cid >> 4;
                    const int kc  = (cid & 15) * 8;
                    const int k   = 128 + kc;
                    const int col = (((k >> 3) ^ (r & 7)) << 3);
                    *(bf16_8*)&As[cur ^ 1][r][col] = a8[c];
                }
            }
        }

        // epilogue for this tile: lane holds 4 consecutive features per frag
        #pragma unroll
        for (int j = 0; j < NJ; ++j) {
            const int n0 = wave_f + j * 16 + quad * 4;
            const float4 b4 = *(const float4*)(bias + n0);
            #pragma unroll
            for (int it = 0; it < 4; ++it) {
                const int token = token0 + it * 16 + l16;
                const float v0 = acc[j][it][0] + b4.x;
                const float v1 = acc[j][it][1] + b4.y;
                const float v2 = acc[j][it][2] + b4.z;
                const float v3 = acc[j][it][3] + b4.w;
                if (MODE == 0) {
                    float4 o; o.x = v0; o.y = v1; o.z = v2; o.w = v3;
                    *(float4*)((float*)Cout + ((size_t)z * tokens + token) * ldc + n0) = o;
                } else {
                    const int mh = n0 >> 5, dd = n0 & 31;
                    bf16_4 ob;
                    ob[0] = (__bf16)v0; ob[1] = (__bf16)v1; ob[2] = (__bf16)v2; ob[3] = (__bf16)v3;
                    *(bf16_4*)((__bf16*)Cout + (((size_t)z * 8 + mh) * NN + token) * 32 + dd) = ob;
                }
            }
        }

        if (more) __syncthreads();
    }
}

// ---------------------------------------------------------------------------
// Fused softmax + bilinear sampling (v4): 4-lanes-per-row gather +
// halving-tree shuffle reduction.  Block = 512 threads = 8 waves (wave = head).
// ---------------------------------------------------------------------------
__device__ __forceinline__ float bflo(unsigned u) { return __uint_as_float(u << 16); }
__device__ __forceinline__ float bfhi(unsigned u) { return __uint_as_float(u & 0xffff0000u); }

__global__ __launch_bounds__(512) void sampler(
    const __bf16* __restrict__ vp,    // [B,8,N,32] bf16
    const float* __restrict__ gqp,    // [B*Q,384]: 0..127 attn logits, 128..383 offsets
    const float* __restrict__ pref,   // [B*Q,4,2]
    __bf16* __restrict__ mid)         // [B*Q,256] bf16
{
    const int t    = threadIdx.x;
    const int m    = t >> 6;
    const int lane = t & 63;
    const int s    = lane >> 2;     // sample 0..15
    const int c    = lane & 3;      // 16B chunk 0..3
    const int l    = s >> 2;        // level
    const int bq   = blockIdx.x;
    const int b    = bq >> 12;      // Q = 4096

    const int   Hi = 128 >> l;      // 128,64,32,16 (square levels)
    const float Hf = (float)Hi;
    const int   base = (l == 0) ? 0 : (l == 1) ? 16384 : (l == 2) ? 20480 : 21504;

    // softmax over the 16 samples of this head (lane bits 2..5); logits O(1)
    const float logit = gqp[(size_t)bq * 384 + m * 16 + s];
    const float e = __expf(logit);
    float sum = e;
    #pragma unroll
    for (int k = 4; k < 64; k <<= 1) sum += __shfl_xor(sum, k, 64);
    const float a = e * __builtin_amdgcn_rcpf(sum);

    const float2 off = *(const float2*)(gqp + (size_t)bq * 384 + 128 + (m * 16 + s) * 2);
    const float2 pr  = *(const float2*)(pref + (size_t)bq * 8 + l * 2);

    const float x = fmaf(pr.x, Hf, off.x - 0.5f);
    const float y = fmaf(pr.y, Hf, off.y - 0.5f);
    const float x0f = floorf(x), y0f = floorf(y);
    const float lx = x - x0f, ly = y - y0f;
    const int x0 = (int)x0f, y0 = (int)y0f;
    const int cx0 = min(max(x0, 0), Hi - 1), cx1 = min(max(x0 + 1, 0), Hi - 1);
    const int cy0 = min(max(y0, 0), Hi - 1), cy1 = min(max(y0 + 1, 0), Hi - 1);
    const bool vx0 = (x0 >= 0) && (x0 < Hi), vx1 = (x0 + 1 >= 0) && (x0 + 1 < Hi);
    const bool vy0 = (y0 >= 0) && (y0 < Hi), vy1 = (y0 + 1 >= 0) && (y0 + 1 < Hi);
    const float w00 = a * (1.f - lx) * (1.f - ly) * ((vx0 && vy0) ? 1.f : 0.f);
    const float w10 = a * lx * (1.f - ly) * ((vx1 && vy0) ? 1.f : 0.f);
    const float w01 = a * (1.f - lx) * ly * ((vx0 && vy1) ? 1.f : 0.f);
    const float w11 = a * lx * ly * ((vx1 && vy1) ? 1.f : 0.f);

    const __bf16* vbase = vp + ((size_t)b * 8 + m) * NN * 32;
    const uint4 u00 = *((const uint4*)(vbase + (size_t)(base + cy0 * Hi + cx0) * 32) + c);
    const uint4 u10 = *((const uint4*)(vbase + (size_t)(base + cy0 * Hi + cx1) * 32) + c);
    const uint4 u01 = *((const uint4*)(vbase + (size_t)(base + cy1 * Hi + cx0) * 32) + c);
    const uint4 u11 = *((const uint4*)(vbase + (size_t)(base + cy1 * Hi + cx1) * 32) + c);

    float f[8];
    f[0] = w00*bflo(u00.x) + w10*bflo(u10.x) + w01*bflo(u01.x) + w11*bflo(u11.x);
    f[1] = w00*bfhi(u00.x) + w10*bfhi(u10.x) + w01*bfhi(u01.x) + w11*bfhi(u11.x);
    f[2] = w00*bflo(u00.y) + w10*bflo(u10.y) + w01*bflo(u01.y) + w11*bflo(u11.y);
    f[3] = w00*bfhi(u00.y) + w10*bfhi(u10.y) + w01*bfhi(u01.y) + w11*bfhi(u11.y);
    f[4] = w00*bflo(u00.z) + w10*bflo(u10.z) + w01*bflo(u01.z) + w11*bflo(u11.z);
    f[5] = w00*bfhi(u00.z) + w10*bfhi(u10.z) + w01*bfhi(u01.z) + w11*bfhi(u11.z);
    f[6] = w00*bflo(u00.w) + w10*bflo(u10.w) + w01*bflo(u01.w) + w11*bflo(u11.w);
    f[7] = w00*bfhi(u00.w) + w10*bfhi(u10.w) + w01*bfhi(u01.w) + w11*bfhi(u11.w);

    // Halving-tree reduction over the 16 samples (lane bits 2..5)
    const int b2 = (lane >> 2) & 1, b3 = (lane >> 3) & 1, b4i = (lane >> 4) & 1;
    #pragma unroll
    for (int j = 0; j < 4; ++j) {
        const float sel  = b2 ? f[j] : f[j + 4];
        const float recv = __shfl_xor(sel, 4, 64);
        f[j] = (b2 ? f[j + 4] : f[j]) + recv;
    }
    #pragma unroll
    for (int j = 0; j < 2; ++j) {
        const float sel  = b3 ? f[j] : f[j + 2];
        const float recv = __shfl_xor(sel, 8, 64);
        f[j] = (b3 ? f[j + 2] : f[j]) + recv;
    }
    {
        const float sel  = b4i ? f[0] : f[1];
        const float recv = __shfl_xor(sel, 16, 64);
        f[0] = (b4i ? f[1] : f[0]) + recv;
    }
    f[0] += __shfl_xor(f[0], 32, 64);

    if (!(lane & 32)) {
        const int chan = (c << 3) | (b2 << 2) | (b3 << 1) | b4i;
        mid[(size_t)bq * 256 + m * 32 + chan] = (__bf16)f[0];
    }
}

extern "C" void kernel_launch(void* const* d_in, const int* in_sizes, int n_in,
                              void* d_out, int out_size, void* d_ws, size_t ws_size,
                              hipStream_t stream) {
    const float* q      = (const float*)d_in[0];
    const float* p      = (const float*)d_in[1];
    const float* v      = (const float*)d_in[2];
    const float* W_off  = (const float*)d_in[5];
    const float* b_off  = (const float*)d_in[6];
    const float* W_attn = (const float*)d_in[7];
    const float* b_attn = (const float*)d_in[8];
    const float* W_val  = (const float*)d_in[9];
    const float* b_val  = (const float*)d_in[10];
    const float* W_out  = (const float*)d_in[11];
    const float* b_out  = (const float*)d_in[12];
    float* out = (float*)d_out;

    // Workspace layout:
    //   gqp   : float [16384*384]
    //   biasq : float [384]
    //   mid   : bf16  [16384*256]
    //   vpb   : bf16  [4*8*21760*32]
    //   Wt    : bf16  [229376]
    float*  gqp   = (float*)d_ws;
    float*  biasq = gqp + (size_t)16384 * 384;
    __bf16* mid   = (__bf16*)(biasq + 384);
    __bf16* vpb   = mid + (size_t)16384 * 256;
    __bf16* Wt    = vpb + (size_t)BB * 8 * NN * 32;
    __bf16* Wt_val  = Wt;
    __bf16* Wt_attn = Wt + 65536;             // rows 0..127 of Wq
    __bf16* Wt_off  = Wt + 65536 + 32768;     // rows 128..383 of Wq
    __bf16* Wt_out  = Wt + 163840;

    // 0) weights -> bf16 transposed (+ fused q-proj bias)
    prep_weights<<<898, 256, 0, stream>>>(W_val, W_attn, W_off, W_out, b_attn, b_off, Wt, biasq);

    // 1) v_p = v @ W_val + b_val -> bf16 [B,8,N,32]  (weight-stationary, TILES=4)
    {
        dim3 grid(1, 340 / 4, BB);                  // (1, 85, 4)
        gemm_ws<float, 256, 1, 4><<<grid, 512, 0, stream>>>(v, Wt_val, b_val, vpb, NN, 0);
    }
    // 2a) attn logits = q @ W_attn + b_attn -> gqp cols 0..127 (ldc 384)
    {
        dim3 grid(1, 256, 1);
        gemm_ws<float, 128, 0, 1><<<grid, 512, 0, stream>>>(q, Wt_attn, biasq, gqp, BB * QQ, 384);
    }
    // 2b) offsets = q @ W_off + b_off -> gqp cols 128..383 (ldc 384)
    {
        dim3 grid(1, 256, 1);
        gemm_ws<float, 256, 0, 1><<<grid, 512, 0, stream>>>(q, Wt_off, biasq + 128, gqp + 128, BB * QQ, 384);
    }
    // 3) softmax + bilinear sampling -> mid bf16 [B*Q,256]
    sampler<<<BB * QQ, 512, 0, stream>>>(vpb, gqp, p, mid);
    // 4) out = mid @ W_out + b_out -> [B,Q,256]
    {
        dim3 grid(1, 256, 1);
        gemm_ws<__bf16, 256, 0, 1><<<grid, 512, 0, stream>>>(mid, Wt_out, b_out, out, BB * QQ, 256);
    }
}